// Round 3
// baseline (878.772 us; speedup 1.0000x reference)
//
#include <hip/hip_runtime.h>
#include <hip/hip_bf16.h>
#include <math.h>

#define NN 8192
#define HD 128
#define NB 2
#define EPSF 1e-6f

typedef __attribute__((ext_vector_type(8))) __bf16 bf16x8;
typedef __attribute__((ext_vector_type(4))) float f32x4;

// ---------------- Kernel 1: norm = rsqrt(sum|adj_row| + eps) -----------------
__global__ __launch_bounds__(256) void k_degree(const float* __restrict__ adj,
                                                float* __restrict__ norm) {
    const int row  = blockIdx.x * 4 + (threadIdx.x >> 6);
    const int lane = threadIdx.x & 63;
    const float4* p = (const float4*)(adj + (size_t)row * NN);
    float s = 0.f;
#pragma unroll
    for (int i = 0; i < 32; ++i) {
        float4 v = p[(size_t)i * 64 + lane];
        s += fabsf(v.x) + fabsf(v.y) + fabsf(v.z) + fabsf(v.w);
    }
#pragma unroll
    for (int off = 32; off > 0; off >>= 1) s += __shfl_down(s, off);
    if (lane == 0) norm[row] = rsqrtf(s + EPSF);
}

// ------- Kernel 2: snT[b][h][n] = bf16( (x@W)[b][n][h] * norm[b][n] ) --------
__global__ __launch_bounds__(256) void k_support(const float* __restrict__ x,
                                                 const float* __restrict__ W,
                                                 const float* __restrict__ norm,
                                                 __hip_bfloat16* __restrict__ snT) {
    const int b  = blockIdx.x >> 9;
    const int n0 = (blockIdx.x & 511) * 16;
    __shared__ float xs[16][132];
    const int t = threadIdx.x;
    {
        const int r = t >> 4, c0 = (t & 15) * 8;
        const float* src = x + ((size_t)(b * NN + n0 + r)) * HD + c0;
        *(float4*)&xs[r][c0]     = *(const float4*)src;
        *(float4*)&xs[r][c0 + 4] = *(const float4*)(src + 4);
    }
    __syncthreads();
    const int nl = t & 15;
    const int h0 = (t >> 4) * 8;
    float s[8] = {0.f,0.f,0.f,0.f,0.f,0.f,0.f,0.f};
#pragma unroll 4
    for (int k = 0; k < HD; ++k) {
        const float xv = xs[nl][k];
        const float* wr = W + k * HD + h0;
        float4 wa = *(const float4*)wr;
        float4 wb = *(const float4*)(wr + 4);
        s[0] += xv * wa.x; s[1] += xv * wa.y; s[2] += xv * wa.z; s[3] += xv * wa.w;
        s[4] += xv * wb.x; s[5] += xv * wb.y; s[6] += xv * wb.z; s[7] += xv * wb.w;
    }
    const float nv = norm[b * NN + n0 + nl];
#pragma unroll
    for (int hb = 0; hb < 8; ++hb)
        snT[((size_t)b * HD + h0 + hb) * NN + n0 + nl] = __float2bfloat16(s[hb] * nv);
}

__device__ inline bf16x8 cvt8(float4 a, float4 b) {
    bf16x8 r;
    r[0] = (__bf16)a.x; r[1] = (__bf16)a.y; r[2] = (__bf16)a.z; r[3] = (__bf16)a.w;
    r[4] = (__bf16)b.x; r[5] = (__bf16)b.y; r[6] = (__bf16)b.z; r[7] = (__bf16)b.w;
    return r;
}

// ---- Kernel 3: out = elu( norm_m * (adj[b] @ snT[b]^T) + bias ) -------------
// Block = 32 m-rows x 128 h; 4 waves split h (32 each). No LDS, no barriers,
// no cross-wave reduction. Per body: 4 A-loads (adj, HBM), 2 B-loads (snT,
// L2), 4 MFMA. Static 4-bank register pipeline: issue order B(i+2), A(i+3),
// compute(i) keeps ~3 bodies of HBM loads in flight per wave (~12 KB), so
// 8 waves/CU sustain the 24.6 GB/s/CU HBM share without barrier lockstep.
// A-duplication across the 4 waves is served by L1/L2 (self-stabilizing:
// laggard waves hit cache and catch up).
__global__ __launch_bounds__(256, 2) void k_gemm3(const float* __restrict__ adj,
                                                  const __hip_bfloat16* __restrict__ snT,
                                                  const float* __restrict__ norm,
                                                  const float* __restrict__ bias,
                                                  float* __restrict__ out) {
    const int b    = blockIdx.y;
    const int m0   = blockIdx.x * 32;
    const int w    = threadIdx.x >> 6;
    const int lane = threadIdx.x & 63;
    const int fr   = lane & 15;
    const int g    = lane >> 4;
    const int h0   = w * 32;

    const float* adjB = adj + (size_t)b * NN * NN;
    const __hip_bfloat16* snB = snT + (size_t)b * HD * NN;

    const float* a0 = adjB + (size_t)(m0 + fr) * NN + g * 8;       // m-tile 0 row
    const float* a1 = a0 + (size_t)16 * NN;                        // m-tile 1 row
    const __hip_bfloat16* bp0 = snB + (size_t)(h0 + fr) * NN + g * 8;  // h-tile 0
    const __hip_bfloat16* bp1 = bp0 + (size_t)16 * NN;                 // h-tile 1

    f32x4 acc[2][2] = {};
    float4 Aa0[4], Ab0[4], Aa1[4], Ab1[4];   // [bank]
    bf16x8 Bf[4][2];                         // [bank][h-tile]

#define PF_A(bank, idx) do { const int ko_ = (idx) * 32;                     \
        Aa0[bank] = *(const float4*)(a0 + ko_);                              \
        Ab0[bank] = *(const float4*)(a0 + ko_ + 4);                          \
        Aa1[bank] = *(const float4*)(a1 + ko_);                              \
        Ab1[bank] = *(const float4*)(a1 + ko_ + 4); } while (0)
#define PF_B(bank, idx) do { const int ko_ = (idx) * 32;                     \
        Bf[bank][0] = *(const bf16x8*)(bp0 + ko_);                           \
        Bf[bank][1] = *(const bf16x8*)(bp1 + ko_); } while (0)
#define BODY(i_) do {                                                        \
        PF_B(((i_) + 2) & 3, ((i_) + 2) & 255);                              \
        PF_A(((i_) + 3) & 3, ((i_) + 3) & 255);                              \
        bf16x8 af0_ = cvt8(Aa0[(i_) & 3], Ab0[(i_) & 3]);                    \
        bf16x8 af1_ = cvt8(Aa1[(i_) & 3], Ab1[(i_) & 3]);                    \
        acc[0][0] = __builtin_amdgcn_mfma_f32_16x16x32_bf16(af0_, Bf[(i_) & 3][0], acc[0][0], 0, 0, 0); \
        acc[0][1] = __builtin_amdgcn_mfma_f32_16x16x32_bf16(af0_, Bf[(i_) & 3][1], acc[0][1], 0, 0, 0); \
        acc[1][0] = __builtin_amdgcn_mfma_f32_16x16x32_bf16(af1_, Bf[(i_) & 3][0], acc[1][0], 0, 0, 0); \
        acc[1][1] = __builtin_amdgcn_mfma_f32_16x16x32_bf16(af1_, Bf[(i_) & 3][1], acc[1][1], 0, 0, 0); \
    } while (0)

    // prologue: A(0..2) -> banks 0..2, B(0..1) -> banks 0..1
    PF_A(0, 0); PF_A(1, 1); PF_A(2, 2);
    PF_B(0, 0); PF_B(1, 1);

#pragma unroll 1
    for (int i4 = 0; i4 < 64; ++i4) {
        const int i = i4 * 4;
        BODY(i); BODY(i + 1); BODY(i + 2); BODY(i + 3);
    }
#undef PF_A
#undef PF_B
#undef BODY

    // ---- fused epilogue: *norm_m + bias, elu ----
    const float* normB = norm + b * NN + m0;
    float* outB = out + ((size_t)b * NN + m0) * HD;
    const float bv0 = bias[h0 + fr];
    const float bv1 = bias[h0 + 16 + fr];
#pragma unroll
    for (int mi = 0; mi < 2; ++mi)
#pragma unroll
        for (int j = 0; j < 4; ++j) {
            const int r = mi * 16 + g * 4 + j;
            const float nm = normB[r];
            float v0 = acc[mi][0][j] * nm + bv0;
            float v1 = acc[mi][1][j] * nm + bv1;
            v0 = v0 > 0.f ? v0 : expm1f(v0);
            v1 = v1 > 0.f ? v1 : expm1f(v1);
            outB[(size_t)r * HD + h0 + fr]      = v0;
            outB[(size_t)r * HD + h0 + 16 + fr] = v1;
        }
}

extern "C" void kernel_launch(void* const* d_in, const int* in_sizes, int n_in,
                              void* d_out, int out_size, void* d_ws, size_t ws_size,
                              hipStream_t stream) {
    const float* x    = (const float*)d_in[0];
    const float* adj  = (const float*)d_in[1];
    const float* W    = (const float*)d_in[2];
    const float* bias = (const float*)d_in[3];
    float* out = (float*)d_out;

    float* norm = (float*)d_ws;                                    // 16384 f32
    __hip_bfloat16* snT = (__hip_bfloat16*)((char*)d_ws + 65536);  // 2x128x8192 bf16 (4 MB)

    k_degree <<<dim3(NB * NN / 4),  dim3(256), 0, stream>>>(adj, norm);
    k_support<<<dim3(NB * NN / 16), dim3(256), 0, stream>>>(x, W, norm, snT);
    k_gemm3  <<<dim3(NN / 32, NB),  dim3(256), 0, stream>>>(adj, snT, norm, bias, out);
}

// Round 4
// 418.234 us; speedup vs baseline: 2.1011x; 2.1011x over previous
//
#include <hip/hip_runtime.h>
#include <hip/hip_bf16.h>
#include <math.h>

#define NN 8192
#define HD 128
#define NB 2
#define EPSF 1e-6f
#define KSPLIT 4
#define KCHUNK (NN / KSPLIT)    // 2048
#define NSTEP (KCHUNK / 32)     // 64 bodies per wave

typedef __attribute__((ext_vector_type(8))) __bf16 bf16x8;
typedef __attribute__((ext_vector_type(4))) float f32x4;

// ---------------- Kernel 1: norm = rsqrt(sum|adj_row| + eps) -----------------
__global__ __launch_bounds__(256) void k_degree(const float* __restrict__ adj,
                                                float* __restrict__ norm) {
    const int row  = blockIdx.x * 4 + (threadIdx.x >> 6);
    const int lane = threadIdx.x & 63;
    const float4* p = (const float4*)(adj + (size_t)row * NN);
    float s = 0.f;
#pragma unroll
    for (int i = 0; i < 32; ++i) {
        float4 v = p[(size_t)i * 64 + lane];
        s += fabsf(v.x) + fabsf(v.y) + fabsf(v.z) + fabsf(v.w);
    }
#pragma unroll
    for (int off = 32; off > 0; off >>= 1) s += __shfl_down(s, off);
    if (lane == 0) norm[row] = rsqrtf(s + EPSF);
}

// ------- Kernel 2: snT[b][h][n] = bf16( (x@W)[b][n][h] * norm[b][n] ) --------
__global__ __launch_bounds__(256) void k_support(const float* __restrict__ x,
                                                 const float* __restrict__ W,
                                                 const float* __restrict__ norm,
                                                 __hip_bfloat16* __restrict__ snT) {
    const int b  = blockIdx.x >> 9;
    const int n0 = (blockIdx.x & 511) * 16;
    __shared__ float xs[16][132];
    const int t = threadIdx.x;
    {
        const int r = t >> 4, c0 = (t & 15) * 8;
        const float* src = x + ((size_t)(b * NN + n0 + r)) * HD + c0;
        *(float4*)&xs[r][c0]     = *(const float4*)src;
        *(float4*)&xs[r][c0 + 4] = *(const float4*)(src + 4);
    }
    __syncthreads();
    const int nl = t & 15;
    const int h0 = (t >> 4) * 8;
    float s[8] = {0.f,0.f,0.f,0.f,0.f,0.f,0.f,0.f};
#pragma unroll 4
    for (int k = 0; k < HD; ++k) {
        const float xv = xs[nl][k];
        const float* wr = W + k * HD + h0;
        float4 wa = *(const float4*)wr;
        float4 wb = *(const float4*)(wr + 4);
        s[0] += xv * wa.x; s[1] += xv * wa.y; s[2] += xv * wa.z; s[3] += xv * wa.w;
        s[4] += xv * wb.x; s[5] += xv * wb.y; s[6] += xv * wb.z; s[7] += xv * wb.w;
    }
    const float nv = norm[b * NN + n0 + nl];
#pragma unroll
    for (int hb = 0; hb < 8; ++hb)
        snT[((size_t)b * HD + h0 + hb) * NN + n0 + nl] = __float2bfloat16(s[hb] * nv);
}

__device__ inline bf16x8 cvt8(float4 a, float4 b) {
    bf16x8 r;
    r[0] = (__bf16)a.x; r[1] = (__bf16)a.y; r[2] = (__bf16)a.z; r[3] = (__bf16)a.w;
    r[4] = (__bf16)b.x; r[5] = (__bf16)b.y; r[6] = (__bf16)b.z; r[7] = (__bf16)b.w;
    return r;
}

// ---- Kernel 3: out = elu( norm_m * (adj[b] @ snT[b]^T) + bias ) -------------
// Block = 16 m-rows x 128 h; 4 waves = 4 K-chunks of 2048. End-of-kernel LDS
// reduce only (no loop barriers). VGPR budget ~105 under the (256,4) 128-cap:
// 4 blocks/CU = 16 waves/CU, latency hidden by TLP. Body order: B(i) issued,
// A-bank reload for i+2 issued, then compute(i): the in-order wait for B(i)
// (issued before the A reload) drains B only, keeping 2 A-bodies in flight.
__global__ __launch_bounds__(256, 4) void k_gemm4(const float* __restrict__ adj,
                                                  const __hip_bfloat16* __restrict__ snT,
                                                  const float* __restrict__ norm,
                                                  const float* __restrict__ bias,
                                                  float* __restrict__ out) {
    const int b    = blockIdx.y;
    const int m0   = blockIdx.x * 16;
    const int w    = threadIdx.x >> 6;     // K-chunk owner
    const int lane = threadIdx.x & 63;
    const int fr   = lane & 15;
    const int g    = lane >> 4;
    const int kbase = w * KCHUNK;

    const float* ap = adj + (size_t)b * NN * NN + (size_t)(m0 + fr) * NN + kbase + g * 8;
    const __hip_bfloat16* bp = snT + ((size_t)b * HD + fr) * NN + kbase + g * 8;

    f32x4 acc[8] = {};
    float4 Aa0, Ab0, Aa1, Ab1;     // bank0 = even k-steps, bank1 = odd k-steps
    bf16x8 Bf[8];

#define LOADA(AaX, AbX, idx) do { const int ko_ = (idx) * 32;                \
        AaX = *(const float4*)(ap + ko_);                                    \
        AbX = *(const float4*)(ap + ko_ + 4); } while (0)
#define LOADB(idx) do { const int ko_ = (idx) * 32;                          \
        _Pragma("unroll")                                                    \
        for (int tt = 0; tt < 8; ++tt)                                       \
            Bf[tt] = *(const bf16x8*)(bp + (size_t)tt * 16 * NN + ko_); } while (0)
#define COMP(AaX, AbX) do {                                                  \
        bf16x8 af_ = cvt8(AaX, AbX);                                         \
        _Pragma("unroll")                                                    \
        for (int tt = 0; tt < 8; ++tt)                                       \
            acc[tt] = __builtin_amdgcn_mfma_f32_16x16x32_bf16(af_, Bf[tt], acc[tt], 0, 0, 0); \
    } while (0)

    LOADA(Aa0, Ab0, 0);
    LOADA(Aa1, Ab1, 1);
#pragma unroll 1
    for (int i = 0; i < NSTEP - 2; i += 2) {
        LOADB(i);
        COMP(Aa0, Ab0);            // consume bank0 (step i)
        LOADA(Aa0, Ab0, i + 2);    // refill bank0 for step i+2
        LOADB(i + 1);
        COMP(Aa1, Ab1);            // consume bank1 (step i+1)
        LOADA(Aa1, Ab1, i + 3);    // refill bank1 for step i+3 (last iter loads
                                   // idx NSTEP+? -> guarded by loop bound below)
    }
    LOADB(NSTEP - 2);
    COMP(Aa0, Ab0);
    LOADB(NSTEP - 1);
    COMP(Aa1, Ab1);
#undef LOADA
#undef LOADB
#undef COMP
    // Note: final loop iteration (i = NSTEP-4) refills bank1 with idx NSTEP-1
    // (valid) and bank0 with idx NSTEP-2 (valid); no OOB. The epilogue COMPs
    // then consume banks loaded with NSTEP-2 / NSTEP-1. Wait -- bank contents
    // at exit: bank0 = NSTEP-2 (loaded at i=NSTEP-4 as i+2), bank1 = NSTEP-1
    // (i+3). Correct.

    // ---- cross-wave (K-split) reduction through LDS ----
    __shared__ float red[16][132];
    for (int wv = 0; wv < KSPLIT; ++wv) {
        if (w == wv) {
#pragma unroll
            for (int tt = 0; tt < 8; ++tt)
#pragma unroll
                for (int j = 0; j < 4; ++j) {
                    const int r = g * 4 + j;
                    const int c = tt * 16 + fr;
                    if (wv == 0) red[r][c] = acc[tt][j];
                    else         red[r][c] += acc[tt][j];
                }
        }
        __syncthreads();
    }

    // ---- fused epilogue: *norm_m + bias, elu, coalesced float4 stores ----
    const int t = threadIdx.x;
    const int r = t >> 4;
    const int c = (t & 15) * 8;
    const float nm = norm[b * NN + m0 + r];
    float* op = out + ((size_t)b * NN + m0 + r) * HD + c;
#pragma unroll
    for (int half = 0; half < 2; ++half) {
        float4 v  = *(const float4*)&red[r][c + half * 4];
        float4 bv = *(const float4*)&bias[c + half * 4];
        float4 o;
        o.x = v.x * nm + bv.x; o.y = v.y * nm + bv.y;
        o.z = v.z * nm + bv.z; o.w = v.w * nm + bv.w;
        o.x = o.x > 0.f ? o.x : expm1f(o.x);
        o.y = o.y > 0.f ? o.y : expm1f(o.y);
        o.z = o.z > 0.f ? o.z : expm1f(o.z);
        o.w = o.w > 0.f ? o.w : expm1f(o.w);
        *(float4*)(op + half * 4) = o;
    }
}

extern "C" void kernel_launch(void* const* d_in, const int* in_sizes, int n_in,
                              void* d_out, int out_size, void* d_ws, size_t ws_size,
                              hipStream_t stream) {
    const float* x    = (const float*)d_in[0];
    const float* adj  = (const float*)d_in[1];
    const float* W    = (const float*)d_in[2];
    const float* bias = (const float*)d_in[3];
    float* out = (float*)d_out;

    float* norm = (float*)d_ws;                                    // 16384 f32
    __hip_bfloat16* snT = (__hip_bfloat16*)((char*)d_ws + 65536);  // 2x128x8192 bf16 (4 MB)

    k_degree <<<dim3(NB * NN / 4),  dim3(256), 0, stream>>>(adj, norm);
    k_support<<<dim3(NB * NN / 16), dim3(256), 0, stream>>>(x, W, norm, snT);
    k_gemm4  <<<dim3(NN / 16, NB),  dim3(256), 0, stream>>>(adj, snT, norm, bias, out);
}

// Round 5
// 279.802 us; speedup vs baseline: 3.1407x; 1.4948x over previous
//
#include <hip/hip_runtime.h>
#include <hip/hip_bf16.h>
#include <math.h>

#define NN 8192
#define HD 128
#define NB 2
#define EPSF 1e-6f
#define BM 32
#define BK 128
#define NSTEP (NN / BK)   // 64

typedef __attribute__((ext_vector_type(8))) __bf16 bf16x8;
typedef __attribute__((ext_vector_type(4))) float f32x4;

// ---------------- Kernel 1: norm = rsqrt(sum|adj_row| + eps) -----------------
__global__ __launch_bounds__(256) void k_degree(const float* __restrict__ adj,
                                                float* __restrict__ norm) {
    const int row  = blockIdx.x * 4 + (threadIdx.x >> 6);
    const int lane = threadIdx.x & 63;
    const float4* p = (const float4*)(adj + (size_t)row * NN);
    float s = 0.f;
#pragma unroll
    for (int i = 0; i < 32; ++i) {
        float4 v = p[(size_t)i * 64 + lane];
        s += fabsf(v.x) + fabsf(v.y) + fabsf(v.z) + fabsf(v.w);
    }
#pragma unroll
    for (int off = 32; off > 0; off >>= 1) s += __shfl_down(s, off);
    if (lane == 0) norm[row] = rsqrtf(s + EPSF);
}

// ------- Kernel 2: snT[b][h][n] = bf16( (x@W)[b][n][h] * norm[b][n] ) --------
__global__ __launch_bounds__(256) void k_support(const float* __restrict__ x,
                                                 const float* __restrict__ W,
                                                 const float* __restrict__ norm,
                                                 __hip_bfloat16* __restrict__ snT) {
    const int b  = blockIdx.x >> 9;
    const int n0 = (blockIdx.x & 511) * 16;
    __shared__ float xs[16][132];
    const int t = threadIdx.x;
    {
        const int r = t >> 4, c0 = (t & 15) * 8;
        const float* src = x + ((size_t)(b * NN + n0 + r)) * HD + c0;
        *(float4*)&xs[r][c0]     = *(const float4*)src;
        *(float4*)&xs[r][c0 + 4] = *(const float4*)(src + 4);
    }
    __syncthreads();
    const int nl = t & 15;
    const int h0 = (t >> 4) * 8;
    float s[8] = {0.f,0.f,0.f,0.f,0.f,0.f,0.f,0.f};
#pragma unroll 4
    for (int k = 0; k < HD; ++k) {
        const float xv = xs[nl][k];
        const float* wr = W + k * HD + h0;
        float4 wa = *(const float4*)wr;
        float4 wb = *(const float4*)(wr + 4);
        s[0] += xv * wa.x; s[1] += xv * wa.y; s[2] += xv * wa.z; s[3] += xv * wa.w;
        s[4] += xv * wb.x; s[5] += xv * wb.y; s[6] += xv * wb.z; s[7] += xv * wb.w;
    }
    const float nv = norm[b * NN + n0 + nl];
#pragma unroll
    for (int hb = 0; hb < 8; ++hb)
        snT[((size_t)b * HD + h0 + hb) * NN + n0 + nl] = __float2bfloat16(s[hb] * nv);
}

__device__ __forceinline__ bf16x8 cvt8(float4 a, float4 b) {
    bf16x8 r;
    r[0] = (__bf16)a.x; r[1] = (__bf16)a.y; r[2] = (__bf16)a.z; r[3] = (__bf16)a.w;
    r[4] = (__bf16)b.x; r[5] = (__bf16)b.y; r[6] = (__bf16)b.z; r[7] = (__bf16)b.w;
    return r;
}

// async global->LDS, 16 B per lane (dest = wave-uniform base + lane*16)
__device__ __forceinline__ void gload_lds16(const float* g, void* l) {
    __builtin_amdgcn_global_load_lds(
        (const __attribute__((address_space(1))) void*)g,
        (__attribute__((address_space(3))) void*)l, 16, 0, 0);
}

// ---- Kernel 3: out = elu( norm_m * (adj[b] @ snT[b]^T) + bias ) -------------
// m97-style barrier-paced pipeline: adj tile (32 rows x 128 k fp32, 16 KB)
// staged via global_load_lds (compiler cannot sink it -- no VGPR dest) into
// double-buffered LDS; one __syncthreads per K-step is the pacing (its
// vmcnt(0) drain moves 16 KB/block/step >> latency*rate). 4 waves split h
// (32 each). LDS linear row-major [32][128] fp32; the 16-way read conflict is
// fixed by XOR-swizzling the 16B-granule index with row&7 on the GLOBAL source
// (stays within one 128B line -> coalescing unaffected) and reading with the
// same XOR (2 lanes/bank = free). B fragments read direct from L2-resident snT.
__global__ __launch_bounds__(256, 2) void k_gemm5(const float* __restrict__ adj,
                                                  const __hip_bfloat16* __restrict__ snT,
                                                  const float* __restrict__ norm,
                                                  const float* __restrict__ bias,
                                                  float* __restrict__ out) {
    const int b    = blockIdx.y;
    const int m0   = blockIdx.x * BM;
    const int w    = threadIdx.x >> 6;     // wave id = h-slice owner (h0 = w*32)
    const int lane = threadIdx.x & 63;
    const int fr   = lane & 15;
    const int g    = lane >> 4;

    const float* adjB = adj + (size_t)b * NN * NN;
    const __hip_bfloat16* snB = snT + (size_t)b * HD * NN;

    __shared__ __align__(16) char Abuf[2][BM * BK * 4];   // 2 x 16 KB

    // staging geometry: wave w, call c covers flat 16B-granules
    // fg = (w*4+c)*64 + lane ; row = fg>>5 (32 granules/row), slot = fg&31;
    // LDS slot holds global granule slot^(row&7)  (involution)
    const float* sptr[4];
#pragma unroll
    for (int c = 0; c < 4; ++c) {
        const int fg   = (w * 4 + c) * 64 + lane;
        const int row  = fg >> 5;
        const int gsrc = (fg & 31) ^ (row & 7);
        sptr[c] = adjB + (size_t)(m0 + row) * NN + gsrc * 4;
    }

    // B base pointers (per h-tile); fragment = bf16x8 at k = s*128 + ks*32 + g*8
    const __hip_bfloat16* bp0 = snB + (size_t)(w * 32 + fr) * NN + g * 8;
    const __hip_bfloat16* bp1 = bp0 + (size_t)16 * NN;

    f32x4 acc[2][2] = {};   // [m-tile][h-tile]
    const int xr = fr & 7;

    // ---- prologue: stage step 0 into buf 0 ----
#pragma unroll
    for (int c = 0; c < 4; ++c)
        gload_lds16(sptr[c], &Abuf[0][(w * 4 + c) * 1024]);

#pragma unroll 1
    for (int s = 0; s < NSTEP; ++s) {
        __syncthreads();               // buf[s&1] staged; prev-step reads done
        const char* lb = Abuf[s & 1];

        // B fragments for this step -- issued BEFORE the next-step stage so
        // their waits leave the stage queue untouched (counted vmcnt)
        bf16x8 Bf[2][4];
#pragma unroll
        for (int ks = 0; ks < 4; ++ks) {
            Bf[0][ks] = *(const bf16x8*)(bp0 + s * BK + ks * 32);
            Bf[1][ks] = *(const bf16x8*)(bp1 + s * BK + ks * 32);
        }

        // stage next adj tile into the other buffer
        if (s + 1 < NSTEP) {
            char* nb = Abuf[(s + 1) & 1];
#pragma unroll
            for (int c = 0; c < 4; ++c)
                gload_lds16(sptr[c] + (s + 1) * BK, &nb[(w * 4 + c) * 1024]);
        }

        // compute from buf[s&1]
#pragma unroll
        for (int mt = 0; mt < 2; ++mt) {
            const char* rbase = lb + (mt * 16 + fr) * 512;
#pragma unroll
            for (int ks = 0; ks < 4; ++ks) {
                float4 fa = *(const float4*)(rbase + ((ks * 8 + ((g * 2 + 0) ^ xr)) << 4));
                float4 fb = *(const float4*)(rbase + ((ks * 8 + ((g * 2 + 1) ^ xr)) << 4));
                bf16x8 af = cvt8(fa, fb);
                acc[mt][0] = __builtin_amdgcn_mfma_f32_16x16x32_bf16(af, Bf[0][ks], acc[mt][0], 0, 0, 0);
                acc[mt][1] = __builtin_amdgcn_mfma_f32_16x16x32_bf16(af, Bf[1][ks], acc[mt][1], 0, 0, 0);
            }
        }
    }

    // ---- fused epilogue: *norm_m + bias, elu ----
    const float* normB = norm + b * NN + m0;
    float* outB = out + ((size_t)b * NN + m0) * HD;
#pragma unroll
    for (int mt = 0; mt < 2; ++mt)
#pragma unroll
        for (int ht = 0; ht < 2; ++ht) {
            const int h  = w * 32 + ht * 16 + fr;
            const float bv = bias[h];
#pragma unroll
            for (int j = 0; j < 4; ++j) {
                const int r = mt * 16 + g * 4 + j;
                float v = acc[mt][ht][j] * normB[r] + bv;
                v = v > 0.f ? v : expm1f(v);
                outB[(size_t)r * HD + h] = v;
            }
        }
}

extern "C" void kernel_launch(void* const* d_in, const int* in_sizes, int n_in,
                              void* d_out, int out_size, void* d_ws, size_t ws_size,
                              hipStream_t stream) {
    (void)in_sizes; (void)n_in; (void)out_size; (void)ws_size;
    const float* x    = (const float*)d_in[0];
    const float* adj  = (const float*)d_in[1];
    const float* W    = (const float*)d_in[2];
    const float* bias = (const float*)d_in[3];
    float* out = (float*)d_out;

    float* norm = (float*)d_ws;                                    // 16384 f32
    __hip_bfloat16* snT = (__hip_bfloat16*)((char*)d_ws + 65536);  // 2x128x8192 bf16 (4 MB)

    k_degree <<<dim3(NB * NN / 4),  dim3(256), 0, stream>>>(adj, norm);
    k_support<<<dim3(NB * NN / 16), dim3(256), 0, stream>>>(x, W, norm, snT);
    k_gemm5  <<<dim3(NN / BM, NB),  dim3(256), 0, stream>>>(adj, snT, norm, bias, out);
}